// Round 9
// baseline (234.082 us; speedup 1.0000x reference)
//
#include <hip/hip_runtime.h>

#define N_BINS 30
#define BLOCK 256
#define GRID 2048
#define T_TOTAL (GRID * BLOCK)    // 524288 threads; <=8 rows/thread @ n=4M

// ECE = sum_b | sum_{i in bin b} (conf_i - correct_i) | / N  (counts cancel).
// R9: R1's max-occupancy fire-and-forget skeleton + run-length-merged LDS
// atomics (flush only on bin change; peaked conf -> ~0.3-0.5 flushes/row).
// All accumulation integer fixed-point (2^20) -> bit-deterministic.

__global__ __launch_bounds__(BLOCK) void ece_hist(
        const float* __restrict__ sm,
        const int*   __restrict__ labels,
        int n,
        unsigned long long* __restrict__ g_sum,
        unsigned int* __restrict__ done,
        float* __restrict__ out) {
    __shared__ int s_whist[4][32];        // per-wave i32 hist (pad 30->32), 512B
    __shared__ unsigned int s_last;

    const int tid  = threadIdx.x;
    const int lane = tid & 63;
    const int wid  = tid >> 6;
    int* whist = s_whist[wid];

    if (lane < 32) whist[lane] = 0;       // wave-private: no barrier needed

    int runBin = -1;                      // run-length merge state (2 VGPRs)
    int runSum = 0;

    for (int r = blockIdx.x * BLOCK + tid; r < n; r += T_TOTAL) {
        const float* row = sm + (long long)r * 10;
        float2 q0 = *reinterpret_cast<const float2*>(row + 0);
        float2 q1 = *reinterpret_cast<const float2*>(row + 2);
        float2 q2 = *reinterpret_cast<const float2*>(row + 4);
        float2 q3 = *reinterpret_cast<const float2*>(row + 6);
        float2 q4 = *reinterpret_cast<const float2*>(row + 8);
        int lbl = labels[r];

        float conf = q0.x; int pred = 0;
        if (q0.y > conf) { conf = q0.y; pred = 1; }
        if (q1.x > conf) { conf = q1.x; pred = 2; }
        if (q1.y > conf) { conf = q1.y; pred = 3; }
        if (q2.x > conf) { conf = q2.x; pred = 4; }
        if (q2.y > conf) { conf = q2.y; pred = 5; }
        if (q3.x > conf) { conf = q3.x; pred = 6; }
        if (q3.y > conf) { conf = q3.y; pred = 7; }
        if (q4.x > conf) { conf = q4.x; pred = 8; }
        if (q4.y > conf) { conf = q4.y; pred = 9; }

        int bin = min(max((int)ceilf(conf * 30.0f) - 1, 0), N_BINS - 1);
        float d = conf - ((pred == lbl) ? 1.0f : 0.0f);
        int dfx = (int)lrintf(d * 1048576.0f);   // 2^20 fixed point, signed

        if (bin == runBin) {
            runSum += dfx;                        // merge into current run
        } else {
            if (runBin >= 0) atomicAdd(&whist[runBin], runSum);  // fire & forget
            runBin = bin;
            runSum = dfx;
        }
    }
    if (runBin >= 0) atomicAdd(&whist[runBin], runSum);

    __syncthreads();

    // ---- block flush: i64 sum of 4 wave hists, one global atomic per bin ----
    if (tid < N_BINS) {
        long long s = (long long)s_whist[0][tid] + (long long)s_whist[1][tid]
                    + (long long)s_whist[2][tid] + (long long)s_whist[3][tid];
        if (s != 0)
            atomicAdd(&g_sum[tid], (unsigned long long)s);   // two's-complement: exact
    }
    __threadfence();
    __syncthreads();

    if (tid == 0)
        s_last = (atomicAdd(done, 1u) == gridDim.x - 1) ? 1u : 0u;
    __syncthreads();

    // ---- last block finalizes ----
    if (s_last && wid == 0) {
        float g = 0.0f;
        if (lane < N_BINS) {
            __threadfence();
            long long v = (long long)atomicAdd(&g_sum[lane], 0ull);  // coherent read
            g = fabsf((float)((double)v * (1.0 / 1048576.0)));
        }
        g += __shfl_xor(g, 1);  g += __shfl_xor(g, 2);  g += __shfl_xor(g, 4);
        g += __shfl_xor(g, 8);  g += __shfl_xor(g, 16); g += __shfl_xor(g, 32);
        if (lane == 0) out[0] = g / (float)n;
    }
}

extern "C" void kernel_launch(void* const* d_in, const int* in_sizes, int n_in,
                              void* d_out, int out_size, void* d_ws, size_t ws_size,
                              hipStream_t stream) {
    const float* sm   = (const float*)d_in[0];
    const int* labels = (const int*)d_in[1];
    const int n = in_sizes[1];   // 4,000,000 rows

    unsigned long long* g_sum = (unsigned long long*)d_ws;
    unsigned int* done = (unsigned int*)(g_sum + N_BINS);

    hipMemsetAsync(d_ws, 0,
                   N_BINS * sizeof(unsigned long long) + sizeof(unsigned int),
                   stream);
    ece_hist<<<GRID, BLOCK, 0, stream>>>(sm, labels, n, g_sum, done,
                                         (float*)d_out);
}